// Round 18
// baseline (167.510 us; speedup 1.0000x reference)
//
#include <hip/hip_runtime.h>
#include <hip/hip_fp16.h>

#define IN_F 128
#define HF   128   // H*F
#define NH   4
#define NF   32

#define NPB       64    // nodes per bucket (matches aggregate granularity)
#define NPB_SHIFT 6
#define NBPAD     1792  // padded bucket count (256*7) for the bin scan
#define BIN_CHUNK 4096  // edges per binning workgroup
#define BCAP      1536  // fixed slots per bucket (mean 1024, +16 sigma)
#define RP        6     // register-staged pairs per thread (6*256 = 1536)

typedef __attribute__((ext_vector_type(8))) short short8v;  // 8 bf16 (4 VGPRs)
typedef __attribute__((ext_vector_type(4))) float f32x4;    // MFMA acc

// bf16 helpers (bit-level, RTN)
__device__ __forceinline__ unsigned short f32_to_bf16_rtn(float f) {
    unsigned int u = __float_as_uint(f);
    u += 0x7fffu + ((u >> 16) & 1u);
    return (unsigned short)(u >> 16);
}

// acc(f32) += f16(lo/hi half of pair) * w(f32) — single VOP3P-MIX instruction.
#define FMA_MIX_LO(acc, pair, w) \
    asm("v_fma_mix_f32 %0, %1, %2, %0 op_sel:[0,0,0] op_sel_hi:[1,0,0]" \
        : "+v"(acc) : "v"(pair), "v"(w))
#define FMA_MIX_HI(acc, pair, w) \
    asm("v_fma_mix_f32 %0, %1, %2, %0 op_sel:[1,0,0] op_sel_hi:[1,0,0]" \
        : "+v"(acc) : "v"(pair), "v"(w))

// ---------------- K0: pack W into MFMA B-fragment layout ----------------
__global__ void __launch_bounds__(256)
gat_wfrag(const float* __restrict__ W, short8v* __restrict__ wfrag) {
    const int entry = blockIdx.x * 256 + threadIdx.x;   // 0..2047
    const int lane = entry & 63;
    const int kb   = (entry >> 6) & 3;
    const int nt   = entry >> 8;
    const int k0   = kb * 32 + (lane >> 4) * 8;
    const int col  = nt * 16 + (lane & 15);
    short8v s;
    #pragma unroll
    for (int j = 0; j < 8; ++j)
        s[j] = (short)f32_to_bf16_rtn(W[(k0 + j) * HF + col]);
    wfrag[entry] = s;
}

// ---------------- shared GEMM block body (MFMA, 64 rows x 128 cols) ----------------
__device__ __forceinline__ void gemm_body(
    int row0b, char* smem,
    const float* __restrict__ feat, const short8v* __restrict__ wfrag,
    const float* __restrict__ attn_l, const float* __restrict__ attn_r,
    unsigned short* __restrict__ feat_src_h,
    float* __restrict__ el, float* __restrict__ er, int N, int t) {
    unsigned short* a_lds = (unsigned short*)smem;            // 16KB
    unsigned short* w_lds = (unsigned short*)(smem + 16384);  // 32KB
    const int lane = t & 63;
    const int wave = t >> 6;

    {
        const uint4* wsrc = (const uint4*)wfrag;
        uint4* wdst = (uint4*)w_lds;
        #pragma unroll
        for (int i = 0; i < 8; ++i)
            wdst[i * 256 + t] = wsrc[i * 256 + t];
    }
    #pragma unroll
    for (int i = 0; i < 8; ++i) {
        int idx = i * 256 + t;           // float4 index, 0..2047
        int row = idx >> 5;
        int c4  = idx & 31;
        int srow = min(row0b + row, N - 1);
        float4 f = *(const float4*)(feat + (size_t)srow * IN_F + c4 * 4);
        unsigned int lo = ((unsigned int)f32_to_bf16_rtn(f.y) << 16) | f32_to_bf16_rtn(f.x);
        unsigned int hi = ((unsigned int)f32_to_bf16_rtn(f.w) << 16) | f32_to_bf16_rtn(f.z);
        int kb = c4 >> 3, g = (c4 >> 1) & 3, half = c4 & 1;
        int wv = row >> 4, m = row & 15;
        unsigned int* p = (unsigned int*)a_lds;
        int u = (wv * 4096 + kb * 1024 + g * 256 + m * 16 + half * 8) >> 2;
        p[u]     = lo;
        p[u + 1] = hi;
    }
    __syncthreads();

    const int m = lane & 15;
    const int g = lane >> 4;
    short8v aw[4];
    #pragma unroll
    for (int kb = 0; kb < 4; ++kb)
        aw[kb] = *(const short8v*)&a_lds[wave * 2048 + kb * 512 + g * 128 + m * 8];

    f32x4 acc[8];
    #pragma unroll
    for (int nt = 0; nt < 8; ++nt) acc[nt] = (f32x4){0.f, 0.f, 0.f, 0.f};

    #pragma unroll
    for (int nt = 0; nt < 8; ++nt) {
        #pragma unroll
        for (int kb = 0; kb < 4; ++kb) {
            short8v bw = *(const short8v*)&w_lds[((nt * 4 + kb) * 64 + lane) * 8];
            acc[nt] = __builtin_amdgcn_mfma_f32_16x16x32_bf16(aw[kb], bw, acc[nt], 0, 0, 0);
        }
    }

    float al[8], ar[8];
    #pragma unroll
    for (int nt = 0; nt < 8; ++nt) {
        al[nt] = attn_l[nt * 16 + m];
        ar[nt] = attn_r[nt * 16 + m];
    }

    #pragma unroll
    for (int r = 0; r < 4; ++r) {
        const int row = row0b + wave * 16 + 4 * g + r;
        const bool valid = (row < N);
        if (valid) {
            #pragma unroll
            for (int nt = 0; nt < 8; ++nt)
                feat_src_h[(size_t)row * HF + nt * 16 + m] =
                    __half_as_ushort(__float2half(acc[nt][r]));
        }
        float pl[NH], pr[NH];
        #pragma unroll
        for (int h = 0; h < NH; ++h) {
            pl[h] = acc[2 * h][r] * al[2 * h] + acc[2 * h + 1][r] * al[2 * h + 1];
            pr[h] = acc[2 * h][r] * ar[2 * h] + acc[2 * h + 1][r] * ar[2 * h + 1];
        }
        #pragma unroll
        for (int mask = 1; mask <= 8; mask <<= 1) {
            #pragma unroll
            for (int h = 0; h < NH; ++h) {
                pl[h] += __shfl_xor(pl[h], mask);
                pr[h] += __shfl_xor(pr[h], mask);
            }
        }
        if (valid && m == 0) {
            *(float4*)(el + (size_t)row * NH) = make_float4(pl[0], pl[1], pl[2], pl[3]);
            *(float4*)(er + (size_t)row * NH) = make_float4(pr[0], pr[1], pr[2], pr[3]);
        }
    }
}

// ---------------- K3: fused {bin (64-node buckets) | full MFMA GEMM} ----------------
// Fixed-capacity buckets: bucket b owns gpairs[b*BCAP .. b*BCAP+BCAP).
// gcursor starts at 0; after this kernel gcursor[b] == bucket count.
__global__ void __launch_bounds__(256)
gat_bin_gemm(const int* __restrict__ src, const int* __restrict__ dst,
             int* __restrict__ gcursor, unsigned int* __restrict__ gpairs, int E,
             int nBin, int nb,
             const float* __restrict__ feat, const short8v* __restrict__ wfrag,
             const float* __restrict__ attn_l, const float* __restrict__ attn_r,
             unsigned short* __restrict__ feat_src_h,
             float* __restrict__ el, float* __restrict__ er, int N) {
    __shared__ __align__(16) char smem[49152];
    const int t = threadIdx.x;

    if ((int)blockIdx.x < nBin) {
        unsigned int*   stage  = (unsigned int*)smem;                 // 16KB
        unsigned short* buckof = (unsigned short*)(smem + 16384);     // 8KB
        int* hist = (int*)(smem + 24576);                             // 7KB [NBPAD]
        int* sc   = (int*)(smem + 31744);                             // 7KB [NBPAD]
        int* cur  = (int*)(smem + 38912);                             // 7KB [NBPAD]
        int* part = (int*)(smem + 46080);                             // 1KB [256]
        // basew reuses hist after scan? no — keep separate via recompute below.
        for (int i = t; i < NBPAD; i += 256) hist[i] = 0;
        __syncthreads();
        const int e0  = blockIdx.x * BIN_CHUNK;
        const int cnt = min(BIN_CHUNK, E - e0);
        for (int i = t; i < cnt; i += 256)
            atomicAdd(&hist[dst[e0 + i] >> NPB_SHIFT], 1);
        __syncthreads();
        // two-level inclusive scan over NBPAD = 256*7 entries
        const int base7 = t * 7;
        int vals[7];
        {
            int run = 0;
            #pragma unroll
            for (int i = 0; i < 7; ++i) { run += hist[base7 + i]; vals[i] = run; }
            part[t] = run;
        }
        __syncthreads();
        for (int off = 1; off < 256; off <<= 1) {
            int x = (t >= off) ? part[t - off] : 0;
            __syncthreads();
            part[t] += x;
            __syncthreads();
        }
        {
            int prev = (t > 0) ? part[t - 1] : 0;
            #pragma unroll
            for (int i = 0; i < 7; ++i) sc[base7 + i] = vals[i] + prev;
        }
        __syncthreads();
        // reserve global ranges; cur = local exclusive scan
        #pragma unroll
        for (int i = 0; i < 7; ++i) {
            int b = base7 + i;
            int c = hist[b];
            cur[b] = sc[b] - c;
            if (b < nb && c) {
                int off0 = atomicAdd(&gcursor[b], c);
                hist[b] = b * BCAP + off0;          // hist now holds global base
            } else {
                hist[b] = -1;
            }
        }
        __syncthreads();
        // NB: hist[b] repurposed as base; need count for ex: recover via cur/sc.
        for (int i = t; i < cnt; i += 256) {
            unsigned s = (unsigned)src[e0 + i];
            unsigned d = (unsigned)dst[e0 + i];
            int b = (int)(d >> NPB_SHIFT);
            int p = atomicAdd(&cur[b], 1);
            stage[p]  = (s << NPB_SHIFT) | (d & (NPB - 1));
            buckof[p] = (unsigned short)b;
        }
        __syncthreads();
        for (int j = t; j < cnt; j += 256) {
            int b  = (int)buckof[j];
            int base = hist[b];
            if (base < 0) continue;
            // ex = sc[b] - count; count = cur[b] - ex  =>  ex = 2*sc[b] - cur[b]... 
            // simpler: after stage, cur[b] == sc[b] (all counted), so ex = sc[b] - c
            // with c = cur[b]_final - ex. Recompute ex from sc and final cur:
            // cur[b] (now) == sc[b]; original c = sc[b] - ex. We stored neither.
            // Use: entries for bucket b occupy stage[ex..sc[b]); j in that range.
            // ex for this j: find via sc[b] - (number of entries) — instead derive
            // local position: pos_in_bucket = j - (sc[b] - (cur[b] - (sc[b] - cur... 
            // cur[b] final == sc[b], so pos = j - (sc[b] - cbCount). cbCount =
            // sc[b] - sc_prev(b) is just the chunk count = original hist.
            // We kept vals/ hist overwritten; recover count = sc[b] - exclusive =
            // sc[b] - (b==0 ? 0 : sc[b-1])  — sc is an inclusive scan, so:
            int ex = (b > 0) ? sc[b - 1] : 0;
            int idx = base + (j - ex);
            if (idx < (b + 1) * BCAP) gpairs[idx] = stage[j];
        }
        return;
    }

    gemm_body((blockIdx.x - nBin) * 64, smem, feat, wfrag, attn_l, attn_r,
              feat_src_h, el, er, N, t);
}

// ---------------- K4: fused fine+aggregate (one WG per 64-node bucket) ----------------
// Phase A: register-stage THIS bucket's slab (no filtering), build 64-node CSR in LDS.
// Phase B: single-pass softmax+aggregation (4-group walk) from LDS slots.
__global__ void __launch_bounds__(256)
gat_fine_agg(const unsigned int* __restrict__ gpairs, const int* __restrict__ counts,
             const unsigned short* __restrict__ feat_src_h,
             const float* __restrict__ el, const float* __restrict__ er,
             const float* __restrict__ bias, float* __restrict__ out, int N) {
    __shared__ int   slot_lds[BCAP];
    __shared__ int   hist[64];
    __shared__ int   sbuf[64];
    __shared__ int   offs[65];
    __shared__ int   cur[64];
    __shared__ float exs[4][64][5];   // [wave][edge][head(+pad)]
    const int t = threadIdx.x;
    const int b = blockIdx.x;
    const int node0 = b << NPB_SHIFT;
    const int beg = b * BCAP;
    const int end = beg + min(counts[b], BCAP);

    if (t < 64) hist[t] = 0;
    __syncthreads();

    // ---- phase A: stage this bucket's pairs in registers, histogram 64 nodes ----
    unsigned int pv[RP];
    #pragma unroll
    for (int r = 0; r < RP; ++r) {
        int idx = beg + r * 256 + t;
        pv[r] = 0xffffffffu;
        if (idx < end) {
            unsigned int pr = gpairs[idx];
            pv[r] = pr;
            atomicAdd(&hist[pr & (NPB - 1)], 1);
        }
    }
    __syncthreads();
    // inclusive scan of hist[0..63]
    if (t < 64) sbuf[t] = hist[t];
    __syncthreads();
    for (int off = 1; off < 64; off <<= 1) {
        int x = (t < 64 && t >= off) ? sbuf[t - off] : 0;
        __syncthreads();
        if (t < 64) sbuf[t] += x;
        __syncthreads();
    }
    if (t < 64) {
        offs[t + 1] = sbuf[t];
        cur[t] = sbuf[t] - hist[t];                // exclusive
        if (t == 0) offs[0] = 0;
    }
    __syncthreads();
    // scatter into LDS CSR
    #pragma unroll
    for (int r = 0; r < RP; ++r) {
        unsigned int pr = pv[r];
        if (pr != 0xffffffffu) {
            int p = atomicAdd(&cur[pr & (NPB - 1)], 1);
            slot_lds[p] = (int)(pr >> NPB_SHIFT);
        }
    }
    __syncthreads();

    // ---- phase B: per-wave node walk (16 nodes per wave) ----
    const int lane = t & 63;
    const int wave = t >> 6;
    const int k  = lane & 15;              // col block: cols 8k..8k+7
    const int g  = lane >> 4;              // edge group 0..3
    const int hm = k >> 2;                 // head of this lane's cols
    const unsigned short* fsp = feat_src_h + 8 * k;
    float4 b0, b1;
    if (g == 0) {
        b0 = *(const float4*)(bias + 8 * k);
        b1 = *(const float4*)(bias + 8 * k + 4);
    }

    for (int i = 0; i < 16; ++i) {
        const int l = wave + 4 * i;
        const int node = node0 + l;
        if (node >= N) break;
        const int s0 = offs[l];
        const int s1 = offs[l + 1];

        const float4 er4 = *(const float4*)(er + (size_t)node * NH);
        float dacc = 0.f;
        float ax0 = 0.f, ax1 = 0.f, ax2 = 0.f, ax3 = 0.f;
        float ax4 = 0.f, ax5 = 0.f, ax6 = 0.f, ax7 = 0.f;

        for (int c = s0; c < s1; c += 64) {
            int idx = c + lane;
            bool vld = idx < s1;
            int s_l = vld ? slot_lds[idx] : 0;
            float4 ev = make_float4(0.f, 0.f, 0.f, 0.f);
            if (vld) ev = *(const float4*)(el + (size_t)s_l * NH);
            float x0 = ev.x + er4.x; x0 = fmaxf(x0, 0.2f * x0);
            float x1 = ev.y + er4.y; x1 = fmaxf(x1, 0.2f * x1);
            float x2 = ev.z + er4.z; x2 = fmaxf(x2, 0.2f * x2);
            float x3 = ev.w + er4.w; x3 = fmaxf(x3, 0.2f * x3);
            exs[wave][lane][0] = vld ? __expf(x0) : 0.f;
            exs[wave][lane][1] = vld ? __expf(x1) : 0.f;
            exs[wave][lane][2] = vld ? __expf(x2) : 0.f;
            exs[wave][lane][3] = vld ? __expf(x3) : 0.f;
            asm volatile("" ::: "memory");
            const int n = min(64, s1 - c);
            int j = g;
            for (; j + 4 < n; j += 8) {
                int jB = j + 4;
                int sA = slot_lds[c + j];
                int sB = slot_lds[c + jB];
                float wA = exs[wave][j][hm];
                float wB = exs[wave][jB][hm];
                uint4 uA = *(const uint4*)(fsp + (size_t)sA * HF);
                uint4 uB = *(const uint4*)(fsp + (size_t)sB * HF);
                dacc += wA + wB;
                FMA_MIX_LO(ax0, uA.x, wA); FMA_MIX_LO(ax0, uB.x, wB);
                FMA_MIX_HI(ax1, uA.x, wA); FMA_MIX_HI(ax1, uB.x, wB);
                FMA_MIX_LO(ax2, uA.y, wA); FMA_MIX_LO(ax2, uB.y, wB);
                FMA_MIX_HI(ax3, uA.y, wA); FMA_MIX_HI(ax3, uB.y, wB);
                FMA_MIX_LO(ax4, uA.z, wA); FMA_MIX_LO(ax4, uB.z, wB);
                FMA_MIX_HI(ax5, uA.z, wA); FMA_MIX_HI(ax5, uB.z, wB);
                FMA_MIX_LO(ax6, uA.w, wA); FMA_MIX_LO(ax6, uB.w, wB);
                FMA_MIX_HI(ax7, uA.w, wA); FMA_MIX_HI(ax7, uB.w, wB);
            }
            if (j < n) {
                int sA = slot_lds[c + j];
                float wA = exs[wave][j][hm];
                uint4 uA = *(const uint4*)(fsp + (size_t)sA * HF);
                dacc += wA;
                FMA_MIX_LO(ax0, uA.x, wA);
                FMA_MIX_HI(ax1, uA.x, wA);
                FMA_MIX_LO(ax2, uA.y, wA);
                FMA_MIX_HI(ax3, uA.y, wA);
                FMA_MIX_LO(ax4, uA.z, wA);
                FMA_MIX_HI(ax5, uA.z, wA);
                FMA_MIX_LO(ax6, uA.w, wA);
                FMA_MIX_HI(ax7, uA.w, wA);
            }
            asm volatile("" ::: "memory");
        }

        // combine 4 edge-groups; dacc becomes denominator for head hm(lane)
        #pragma unroll
        for (int msk = 16; msk <= 32; msk <<= 1) {
            ax0 += __shfl_xor(ax0, msk); ax1 += __shfl_xor(ax1, msk);
            ax2 += __shfl_xor(ax2, msk); ax3 += __shfl_xor(ax3, msk);
            ax4 += __shfl_xor(ax4, msk); ax5 += __shfl_xor(ax5, msk);
            ax6 += __shfl_xor(ax6, msk); ax7 += __shfl_xor(ax7, msk);
            dacc += __shfl_xor(dacc, msk);
        }
        const float inv = 1.0f / fmaxf(dacc, 1e-9f);

        if (g == 0) {
            float4 o0, o1;
            o0.x = ax0 * inv + b0.x; o0.y = ax1 * inv + b0.y;
            o0.z = ax2 * inv + b0.z; o0.w = ax3 * inv + b0.w;
            o1.x = ax4 * inv + b1.x; o1.y = ax5 * inv + b1.y;
            o1.z = ax6 * inv + b1.z; o1.w = ax7 * inv + b1.w;
            *(float4*)(out + (size_t)node * HF + 8 * k)     = o0;
            *(float4*)(out + (size_t)node * HF + 8 * k + 4) = o1;
        }
    }
}

extern "C" void kernel_launch(void* const* d_in, const int* in_sizes, int n_in,
                              void* d_out, int out_size, void* d_ws, size_t ws_size,
                              hipStream_t stream) {
    const float* feat   = (const float*)d_in[0];
    const float* W      = (const float*)d_in[1];
    const float* attn_l = (const float*)d_in[2];
    const float* attn_r = (const float*)d_in[3];
    const float* bias   = (const float*)d_in[4];
    const int*   src    = (const int*)d_in[5];
    const int*   dst    = (const int*)d_in[6];
    float* out = (float*)d_out;

    const int N = in_sizes[0] / IN_F;
    const int E = in_sizes[5];
    const int nb = (N + NPB - 1) / NPB;         // 1563 buckets of 64 nodes

    char* ws = (char*)d_ws;
    size_t off = 0;
    auto alloc = [&](size_t bytes) -> void* {
        off = (off + 255) & ~(size_t)255;
        void* p = ws + off;
        off += bytes;
        return p;
    };
    unsigned short* feat_src_h = (unsigned short*)alloc((size_t)N * HF * sizeof(unsigned short));
    float* el      = (float*)alloc((size_t)N * NH * sizeof(float));
    float* er      = (float*)alloc((size_t)N * NH * sizeof(float));
    int*   gcursor = (int*)  alloc((size_t)nb * sizeof(int));
    unsigned int* gpairs = (unsigned int*)alloc((size_t)nb * BCAP * sizeof(unsigned int));
    short8v* wfrag = (short8v*)alloc((size_t)2048 * sizeof(short8v));   // 32KB

    hipMemsetAsync(gcursor, 0, (size_t)nb * sizeof(int), stream);

    gat_wfrag<<<8, 256, 0, stream>>>(W, wfrag);

    const int nBin = (E + BIN_CHUNK - 1) / BIN_CHUNK;
    const int gemmBlocks = (N + 63) / 64;
    gat_bin_gemm<<<nBin + gemmBlocks, 256, 0, stream>>>(
        src, dst, gcursor, gpairs, E, nBin, nb,
        feat, wfrag, attn_l, attn_r, feat_src_h, el, er, N);

    gat_fine_agg<<<nb, 256, 0, stream>>>(
        gpairs, gcursor, feat_src_h, el, er, bias, out, N);
}

// Round 19
// 131.346 us; speedup vs baseline: 1.2753x; 1.2753x over previous
//
#include <hip/hip_runtime.h>
#include <hip/hip_fp16.h>

#define IN_F 128
#define HF   128   // H*F
#define NH   4
#define NF   32

#define NPB       256   // nodes per coarse bucket
#define NPB_SHIFT 8
#define BIN_CHUNK 4096  // edges per binning workgroup
#define BCAP      4608  // fixed slots per bucket (mean 4092, +8 sigma)
#define QCAP 1536       // slot capacity per quarter-bucket
#define RP   18         // register-staged pairs per thread (18*256 = 4608)

typedef __attribute__((ext_vector_type(8))) short short8v;  // 8 bf16 (4 VGPRs)
typedef __attribute__((ext_vector_type(4))) float f32x4;    // MFMA acc

// bf16 helpers (bit-level, RTN)
__device__ __forceinline__ unsigned short f32_to_bf16_rtn(float f) {
    unsigned int u = __float_as_uint(f);
    u += 0x7fffu + ((u >> 16) & 1u);
    return (unsigned short)(u >> 16);
}

// acc(f32) += f16(lo/hi half of pair) * w(f32) — single VOP3P-MIX instruction.
#define FMA_MIX_LO(acc, pair, w) \
    asm("v_fma_mix_f32 %0, %1, %2, %0 op_sel:[0,0,0] op_sel_hi:[1,0,0]" \
        : "+v"(acc) : "v"(pair), "v"(w))
#define FMA_MIX_HI(acc, pair, w) \
    asm("v_fma_mix_f32 %0, %1, %2, %0 op_sel:[1,0,0] op_sel_hi:[1,0,0]" \
        : "+v"(acc) : "v"(pair), "v"(w))

// ---------------- K0: pack W into MFMA B-fragment layout ----------------
__global__ void __launch_bounds__(256)
gat_wfrag(const float* __restrict__ W, short8v* __restrict__ wfrag) {
    const int entry = blockIdx.x * 256 + threadIdx.x;   // 0..2047
    const int lane = entry & 63;
    const int kb   = (entry >> 6) & 3;
    const int nt   = entry >> 8;
    const int k0   = kb * 32 + (lane >> 4) * 8;
    const int col  = nt * 16 + (lane & 15);
    short8v s;
    #pragma unroll
    for (int j = 0; j < 8; ++j)
        s[j] = (short)f32_to_bf16_rtn(W[(k0 + j) * HF + col]);
    wfrag[entry] = s;
}

// ---------------- shared GEMM block body (MFMA, 64 rows x 128 cols) ----------------
__device__ __forceinline__ void gemm_body(
    int row0b, char* smem,
    const float* __restrict__ feat, const short8v* __restrict__ wfrag,
    const float* __restrict__ attn_l, const float* __restrict__ attn_r,
    unsigned short* __restrict__ feat_src_h,
    float* __restrict__ el, float* __restrict__ er, int N, int t) {
    unsigned short* a_lds = (unsigned short*)smem;            // 16KB
    unsigned short* w_lds = (unsigned short*)(smem + 16384);  // 32KB
    const int lane = t & 63;
    const int wave = t >> 6;

    {
        const uint4* wsrc = (const uint4*)wfrag;
        uint4* wdst = (uint4*)w_lds;
        #pragma unroll
        for (int i = 0; i < 8; ++i)
            wdst[i * 256 + t] = wsrc[i * 256 + t];
    }
    #pragma unroll
    for (int i = 0; i < 8; ++i) {
        int idx = i * 256 + t;           // float4 index, 0..2047
        int row = idx >> 5;
        int c4  = idx & 31;
        int srow = min(row0b + row, N - 1);
        float4 f = *(const float4*)(feat + (size_t)srow * IN_F + c4 * 4);
        unsigned int lo = ((unsigned int)f32_to_bf16_rtn(f.y) << 16) | f32_to_bf16_rtn(f.x);
        unsigned int hi = ((unsigned int)f32_to_bf16_rtn(f.w) << 16) | f32_to_bf16_rtn(f.z);
        int kb = c4 >> 3, g = (c4 >> 1) & 3, half = c4 & 1;
        int wv = row >> 4, m = row & 15;
        unsigned int* p = (unsigned int*)a_lds;
        int u = (wv * 4096 + kb * 1024 + g * 256 + m * 16 + half * 8) >> 2;
        p[u]     = lo;
        p[u + 1] = hi;
    }
    __syncthreads();

    const int m = lane & 15;
    const int g = lane >> 4;
    short8v aw[4];
    #pragma unroll
    for (int kb = 0; kb < 4; ++kb)
        aw[kb] = *(const short8v*)&a_lds[wave * 2048 + kb * 512 + g * 128 + m * 8];

    f32x4 acc[8];
    #pragma unroll
    for (int nt = 0; nt < 8; ++nt) acc[nt] = (f32x4){0.f, 0.f, 0.f, 0.f};

    #pragma unroll
    for (int nt = 0; nt < 8; ++nt) {
        #pragma unroll
        for (int kb = 0; kb < 4; ++kb) {
            short8v bw = *(const short8v*)&w_lds[((nt * 4 + kb) * 64 + lane) * 8];
            acc[nt] = __builtin_amdgcn_mfma_f32_16x16x32_bf16(aw[kb], bw, acc[nt], 0, 0, 0);
        }
    }

    float al[8], ar[8];
    #pragma unroll
    for (int nt = 0; nt < 8; ++nt) {
        al[nt] = attn_l[nt * 16 + m];
        ar[nt] = attn_r[nt * 16 + m];
    }

    #pragma unroll
    for (int r = 0; r < 4; ++r) {
        const int row = row0b + wave * 16 + 4 * g + r;
        const bool valid = (row < N);
        if (valid) {
            #pragma unroll
            for (int nt = 0; nt < 8; ++nt)
                feat_src_h[(size_t)row * HF + nt * 16 + m] =
                    __half_as_ushort(__float2half(acc[nt][r]));
        }
        float pl[NH], pr[NH];
        #pragma unroll
        for (int h = 0; h < NH; ++h) {
            pl[h] = acc[2 * h][r] * al[2 * h] + acc[2 * h + 1][r] * al[2 * h + 1];
            pr[h] = acc[2 * h][r] * ar[2 * h] + acc[2 * h + 1][r] * ar[2 * h + 1];
        }
        #pragma unroll
        for (int mask = 1; mask <= 8; mask <<= 1) {
            #pragma unroll
            for (int h = 0; h < NH; ++h) {
                pl[h] += __shfl_xor(pl[h], mask);
                pr[h] += __shfl_xor(pr[h], mask);
            }
        }
        if (valid && m == 0) {
            *(float4*)(el + (size_t)row * NH) = make_float4(pl[0], pl[1], pl[2], pl[3]);
            *(float4*)(er + (size_t)row * NH) = make_float4(pr[0], pr[1], pr[2], pr[3]);
        }
    }
}

// ---------------- K3: fused {bin | full MFMA GEMM} ----------------
// Fixed-capacity buckets: bucket b owns gpairs[b*BCAP .. b*BCAP+BCAP).
// gcursor starts at 0; after this kernel gcursor[b] == bucket count.
__global__ void __launch_bounds__(256)
gat_bin_gemm(const int* __restrict__ src, const int* __restrict__ dst,
             int* __restrict__ gcursor, unsigned int* __restrict__ gpairs, int E,
             int nBin,
             const float* __restrict__ feat, const short8v* __restrict__ wfrag,
             const float* __restrict__ attn_l, const float* __restrict__ attn_r,
             unsigned short* __restrict__ feat_src_h,
             float* __restrict__ el, float* __restrict__ er, int N) {
    __shared__ __align__(16) char smem[49152];
    const int t = threadIdx.x;

    if ((int)blockIdx.x < nBin) {
        unsigned int*   stage  = (unsigned int*)smem;                 // 16KB
        unsigned short* buckof = (unsigned short*)(smem + 16384);     // 8KB
        int* hist  = (int*)(smem + 24576);                            // 2KB
        int* sc    = (int*)(smem + 26624);                            // 2KB
        int* basew = (int*)(smem + 28672);                            // 2KB
        int* cur   = (int*)(smem + 30720);                            // 2KB
        for (int i = t; i < 512; i += 256) hist[i] = 0;
        __syncthreads();
        const int e0  = blockIdx.x * BIN_CHUNK;
        const int cnt = min(BIN_CHUNK, E - e0);
        for (int i = t; i < cnt; i += 256)
            atomicAdd(&hist[dst[e0 + i] >> NPB_SHIFT], 1);
        __syncthreads();
        sc[t]       = hist[t];
        sc[t + 256] = hist[t + 256];
        __syncthreads();
        for (int off = 1; off < 512; off <<= 1) {
            int x0 = (t >= off) ? sc[t - off] : 0;
            int x1 = sc[t + 256 - off];
            __syncthreads();
            sc[t]       += x0;
            sc[t + 256] += x1;
            __syncthreads();
        }
        for (int b = t; b < 512; b += 256) {
            int c  = hist[b];
            int ex = sc[b] - c;
            cur[b] = ex;
            basew[b] = c ? (b * BCAP + atomicAdd(&gcursor[b], c)) : 0;
        }
        __syncthreads();
        for (int i = t; i < cnt; i += 256) {
            unsigned s = (unsigned)src[e0 + i];
            unsigned d = (unsigned)dst[e0 + i];
            int b = (int)(d >> NPB_SHIFT);
            int p = atomicAdd(&cur[b], 1);
            stage[p]  = (s << 8) | (d & (NPB - 1));
            buckof[p] = (unsigned short)b;
        }
        __syncthreads();
        for (int j = t; j < cnt; j += 256) {
            int b  = (int)buckof[j];
            int ex = sc[b] - hist[b];
            gpairs[basew[b] + (j - ex)] = stage[j];
        }
        return;
    }

    gemm_body((blockIdx.x - nBin) * 64, smem, feat, wfrag, attn_l, attn_r,
              feat_src_h, el, er, N, t);
}

// ---------------- K4: fused fine+aggregate (one WG per quarter-bucket) ----------------
// Phase A: register-stage the bucket's pairs, build the 64-node CSR in LDS.
// Phase B: single-pass softmax+aggregation; 4-deep gather unroll -> a 16-edge
// node completes in ONE group-round with 16 rows in flight per wave.
__global__ void __launch_bounds__(256)
gat_fine_agg(const unsigned int* __restrict__ gpairs, const int* __restrict__ counts,
             const unsigned short* __restrict__ feat_src_h,
             const float* __restrict__ el, const float* __restrict__ er,
             const float* __restrict__ bias, float* __restrict__ out, int N) {
    __shared__ int   slot_lds[QCAP];
    __shared__ int   hist[64];
    __shared__ int   sbuf[64];
    __shared__ int   offs[65];
    __shared__ int   cur[64];
    __shared__ float exs[4][64][5];   // [wave][edge][head(+pad)]
    const int t = threadIdx.x;
    const int b = blockIdx.x >> 2;
    const int q = blockIdx.x & 3;
    const int node0 = (b << NPB_SHIFT) + q * 64;
    const int beg = b * BCAP;
    const int end = beg + counts[b];

    if (t < 64) hist[t] = 0;
    __syncthreads();

    // ---- phase A: stage pairs in registers, histogram my 64 nodes ----
    unsigned int pv[RP];
    #pragma unroll
    for (int r = 0; r < RP; ++r) {
        int idx = beg + r * 256 + t;
        pv[r] = 0xffffffffu;                       // impossible pair (src < 2^17)
        if (idx < end) {
            unsigned int pr = gpairs[idx];
            pv[r] = pr;
            int local = (int)(pr & (NPB - 1)) - q * 64;
            if (local >= 0 && local < 64) atomicAdd(&hist[local], 1);
        }
    }
    __syncthreads();
    // inclusive scan of hist[0..63]
    if (t < 64) sbuf[t] = hist[t];
    __syncthreads();
    for (int off = 1; off < 64; off <<= 1) {
        int x = (t < 64 && t >= off) ? sbuf[t - off] : 0;
        __syncthreads();
        if (t < 64) sbuf[t] += x;
        __syncthreads();
    }
    if (t < 64) {
        offs[t + 1] = sbuf[t];
        cur[t] = sbuf[t] - hist[t];                // exclusive
        if (t == 0) offs[0] = 0;
    }
    __syncthreads();
    // scatter into LDS CSR
    #pragma unroll
    for (int r = 0; r < RP; ++r) {
        unsigned int pr = pv[r];
        if (pr != 0xffffffffu) {
            int local = (int)(pr & (NPB - 1)) - q * 64;
            if (local >= 0 && local < 64) {
                int p = atomicAdd(&cur[local], 1);
                slot_lds[p] = (int)(pr >> 8);
            }
        }
    }
    __syncthreads();

    // ---- phase B: per-wave node walk (16 nodes per wave) ----
    const int lane = t & 63;
    const int wave = t >> 6;
    const int k  = lane & 15;              // col block: cols 8k..8k+7
    const int g  = lane >> 4;              // edge group 0..3
    const int hm = k >> 2;                 // head of this lane's cols
    const unsigned short* fsp = feat_src_h + 8 * k;
    float4 b0, b1;
    if (g == 0) {
        b0 = *(const float4*)(bias + 8 * k);
        b1 = *(const float4*)(bias + 8 * k + 4);
    }

    for (int i = 0; i < 16; ++i) {
        const int l = wave + 4 * i;
        const int node = node0 + l;
        if (node >= N) break;
        const int s0 = offs[l];
        const int s1 = offs[l + 1];

        const float4 er4 = *(const float4*)(er + (size_t)node * NH);
        float dacc = 0.f;
        float ax0 = 0.f, ax1 = 0.f, ax2 = 0.f, ax3 = 0.f;
        float ax4 = 0.f, ax5 = 0.f, ax6 = 0.f, ax7 = 0.f;

        for (int c = s0; c < s1; c += 64) {
            int idx = c + lane;
            bool vld = idx < s1;
            int s_l = vld ? slot_lds[idx] : 0;
            float4 ev = make_float4(0.f, 0.f, 0.f, 0.f);
            if (vld) ev = *(const float4*)(el + (size_t)s_l * NH);
            float x0 = ev.x + er4.x; x0 = fmaxf(x0, 0.2f * x0);
            float x1 = ev.y + er4.y; x1 = fmaxf(x1, 0.2f * x1);
            float x2 = ev.z + er4.z; x2 = fmaxf(x2, 0.2f * x2);
            float x3 = ev.w + er4.w; x3 = fmaxf(x3, 0.2f * x3);
            exs[wave][lane][0] = vld ? __expf(x0) : 0.f;
            exs[wave][lane][1] = vld ? __expf(x1) : 0.f;
            exs[wave][lane][2] = vld ? __expf(x2) : 0.f;
            exs[wave][lane][3] = vld ? __expf(x3) : 0.f;
            asm volatile("" ::: "memory");
            const int n = min(64, s1 - c);
            int j = g;
            // 4-deep: 16 gathers in flight per wave (typ. node done in one round)
            for (; j + 12 < n; j += 16) {
                int j1 = j + 4, j2 = j + 8, j3 = j + 12;
                int sA = slot_lds[c + j];
                int sB = slot_lds[c + j1];
                int sC = slot_lds[c + j2];
                int sD = slot_lds[c + j3];
                float wA = exs[wave][j][hm];
                float wB = exs[wave][j1][hm];
                float wC = exs[wave][j2][hm];
                float wD = exs[wave][j3][hm];
                uint4 uA = *(const uint4*)(fsp + (size_t)sA * HF);
                uint4 uB = *(const uint4*)(fsp + (size_t)sB * HF);
                uint4 uC = *(const uint4*)(fsp + (size_t)sC * HF);
                uint4 uD = *(const uint4*)(fsp + (size_t)sD * HF);
                dacc += (wA + wB) + (wC + wD);
                FMA_MIX_LO(ax0, uA.x, wA); FMA_MIX_LO(ax0, uB.x, wB);
                FMA_MIX_LO(ax0, uC.x, wC); FMA_MIX_LO(ax0, uD.x, wD);
                FMA_MIX_HI(ax1, uA.x, wA); FMA_MIX_HI(ax1, uB.x, wB);
                FMA_MIX_HI(ax1, uC.x, wC); FMA_MIX_HI(ax1, uD.x, wD);
                FMA_MIX_LO(ax2, uA.y, wA); FMA_MIX_LO(ax2, uB.y, wB);
                FMA_MIX_LO(ax2, uC.y, wC); FMA_MIX_LO(ax2, uD.y, wD);
                FMA_MIX_HI(ax3, uA.y, wA); FMA_MIX_HI(ax3, uB.y, wB);
                FMA_MIX_HI(ax3, uC.y, wC); FMA_MIX_HI(ax3, uD.y, wD);
                FMA_MIX_LO(ax4, uA.z, wA); FMA_MIX_LO(ax4, uB.z, wB);
                FMA_MIX_LO(ax4, uC.z, wC); FMA_MIX_LO(ax4, uD.z, wD);
                FMA_MIX_HI(ax5, uA.z, wA); FMA_MIX_HI(ax5, uB.z, wB);
                FMA_MIX_HI(ax5, uC.z, wC); FMA_MIX_HI(ax5, uD.z, wD);
                FMA_MIX_LO(ax6, uA.w, wA); FMA_MIX_LO(ax6, uB.w, wB);
                FMA_MIX_LO(ax6, uC.w, wC); FMA_MIX_LO(ax6, uD.w, wD);
                FMA_MIX_HI(ax7, uA.w, wA); FMA_MIX_HI(ax7, uB.w, wB);
                FMA_MIX_HI(ax7, uC.w, wC); FMA_MIX_HI(ax7, uD.w, wD);
            }
            for (; j + 4 < n; j += 8) {
                int jB = j + 4;
                int sA = slot_lds[c + j];
                int sB = slot_lds[c + jB];
                float wA = exs[wave][j][hm];
                float wB = exs[wave][jB][hm];
                uint4 uA = *(const uint4*)(fsp + (size_t)sA * HF);
                uint4 uB = *(const uint4*)(fsp + (size_t)sB * HF);
                dacc += wA + wB;
                FMA_MIX_LO(ax0, uA.x, wA); FMA_MIX_LO(ax0, uB.x, wB);
                FMA_MIX_HI(ax1, uA.x, wA); FMA_MIX_HI(ax1, uB.x, wB);
                FMA_MIX_LO(ax2, uA.y, wA); FMA_MIX_LO(ax2, uB.y, wB);
                FMA_MIX_HI(ax3, uA.y, wA); FMA_MIX_HI(ax3, uB.y, wB);
                FMA_MIX_LO(ax4, uA.z, wA); FMA_MIX_LO(ax4, uB.z, wB);
                FMA_MIX_HI(ax5, uA.z, wA); FMA_MIX_HI(ax5, uB.z, wB);
                FMA_MIX_LO(ax6, uA.w, wA); FMA_MIX_LO(ax6, uB.w, wB);
                FMA_MIX_HI(ax7, uA.w, wA); FMA_MIX_HI(ax7, uB.w, wB);
            }
            if (j < n) {
                int sA = slot_lds[c + j];
                float wA = exs[wave][j][hm];
                uint4 uA = *(const uint4*)(fsp + (size_t)sA * HF);
                dacc += wA;
                FMA_MIX_LO(ax0, uA.x, wA);
                FMA_MIX_HI(ax1, uA.x, wA);
                FMA_MIX_LO(ax2, uA.y, wA);
                FMA_MIX_HI(ax3, uA.y, wA);
                FMA_MIX_LO(ax4, uA.z, wA);
                FMA_MIX_HI(ax5, uA.z, wA);
                FMA_MIX_LO(ax6, uA.w, wA);
                FMA_MIX_HI(ax7, uA.w, wA);
            }
            asm volatile("" ::: "memory");
        }

        // combine 4 edge-groups; dacc becomes denominator for head hm(lane)
        #pragma unroll
        for (int msk = 16; msk <= 32; msk <<= 1) {
            ax0 += __shfl_xor(ax0, msk); ax1 += __shfl_xor(ax1, msk);
            ax2 += __shfl_xor(ax2, msk); ax3 += __shfl_xor(ax3, msk);
            ax4 += __shfl_xor(ax4, msk); ax5 += __shfl_xor(ax5, msk);
            ax6 += __shfl_xor(ax6, msk); ax7 += __shfl_xor(ax7, msk);
            dacc += __shfl_xor(dacc, msk);
        }
        const float inv = 1.0f / fmaxf(dacc, 1e-9f);

        if (g == 0) {
            float4 o0, o1;
            o0.x = ax0 * inv + b0.x; o0.y = ax1 * inv + b0.y;
            o0.z = ax2 * inv + b0.z; o0.w = ax3 * inv + b0.w;
            o1.x = ax4 * inv + b1.x; o1.y = ax5 * inv + b1.y;
            o1.z = ax6 * inv + b1.z; o1.w = ax7 * inv + b1.w;
            *(float4*)(out + (size_t)node * HF + 8 * k)     = o0;
            *(float4*)(out + (size_t)node * HF + 8 * k + 4) = o1;
        }
    }
}

extern "C" void kernel_launch(void* const* d_in, const int* in_sizes, int n_in,
                              void* d_out, int out_size, void* d_ws, size_t ws_size,
                              hipStream_t stream) {
    const float* feat   = (const float*)d_in[0];
    const float* W      = (const float*)d_in[1];
    const float* attn_l = (const float*)d_in[2];
    const float* attn_r = (const float*)d_in[3];
    const float* bias   = (const float*)d_in[4];
    const int*   src    = (const int*)d_in[5];
    const int*   dst    = (const int*)d_in[6];
    float* out = (float*)d_out;

    const int N = in_sizes[0] / IN_F;
    const int E = in_sizes[5];
    const int nbuck = (N + NPB - 1) / NPB;      // 391 for N=100000

    char* ws = (char*)d_ws;
    size_t off = 0;
    auto alloc = [&](size_t bytes) -> void* {
        off = (off + 255) & ~(size_t)255;
        void* p = ws + off;
        off += bytes;
        return p;
    };
    unsigned short* feat_src_h = (unsigned short*)alloc((size_t)N * HF * sizeof(unsigned short));
    float* el      = (float*)alloc((size_t)N * NH * sizeof(float));
    float* er      = (float*)alloc((size_t)N * NH * sizeof(float));
    int*   gcursor = (int*)  alloc((size_t)nbuck * sizeof(int));
    unsigned int* gpairs = (unsigned int*)alloc((size_t)nbuck * BCAP * sizeof(unsigned int));
    short8v* wfrag = (short8v*)alloc((size_t)2048 * sizeof(short8v));   // 32KB

    hipMemsetAsync(gcursor, 0, (size_t)nbuck * sizeof(int), stream);

    gat_wfrag<<<8, 256, 0, stream>>>(W, wfrag);

    const int nBin = (E + BIN_CHUNK - 1) / BIN_CHUNK;
    const int gemmBlocks = (N + 63) / 64;
    gat_bin_gemm<<<nBin + gemmBlocks, 256, 0, stream>>>(
        src, dst, gcursor, gpairs, E, nBin,
        feat, wfrag, attn_l, attn_r, feat_src_h, el, er, N);

    gat_fine_agg<<<nbuck * 4, 256, 0, stream>>>(
        gpairs, gcursor, feat_src_h, el, er, bias, out, N);
}

// Round 20
// 130.529 us; speedup vs baseline: 1.2833x; 1.0063x over previous
//
#include <hip/hip_runtime.h>
#include <hip/hip_fp16.h>

#define IN_F 128
#define HF   128   // H*F
#define NH   4
#define NF   32

#define NPB       256   // nodes per coarse bucket
#define NPB_SHIFT 8
#define BIN_CHUNK 4096  // edges per binning workgroup
#define BCAP      4608  // fixed slots per bucket (mean 4092, +8 sigma)
#define QCAP 1536       // slot capacity per quarter-bucket
#define RP   18         // register-staged pairs per thread (18*256 = 4608)

typedef __attribute__((ext_vector_type(8))) short short8v;  // 8 bf16 (4 VGPRs)
typedef __attribute__((ext_vector_type(4))) float f32x4;    // MFMA acc

// bf16 helpers (bit-level, RTN)
__device__ __forceinline__ unsigned short f32_to_bf16_rtn(float f) {
    unsigned int u = __float_as_uint(f);
    u += 0x7fffu + ((u >> 16) & 1u);
    return (unsigned short)(u >> 16);
}

// acc(f32) += f16(lo/hi half of pair) * w(f32) — single VOP3P-MIX instruction.
#define FMA_MIX_LO(acc, pair, w) \
    asm("v_fma_mix_f32 %0, %1, %2, %0 op_sel:[0,0,0] op_sel_hi:[1,0,0]" \
        : "+v"(acc) : "v"(pair), "v"(w))
#define FMA_MIX_HI(acc, pair, w) \
    asm("v_fma_mix_f32 %0, %1, %2, %0 op_sel:[1,0,0] op_sel_hi:[1,0,0]" \
        : "+v"(acc) : "v"(pair), "v"(w))

// ---------------- K0: pack W into MFMA B-fragment layout ----------------
__global__ void __launch_bounds__(256)
gat_wfrag(const float* __restrict__ W, short8v* __restrict__ wfrag) {
    const int entry = blockIdx.x * 256 + threadIdx.x;   // 0..2047
    const int lane = entry & 63;
    const int kb   = (entry >> 6) & 3;
    const int nt   = entry >> 8;
    const int k0   = kb * 32 + (lane >> 4) * 8;
    const int col  = nt * 16 + (lane & 15);
    short8v s;
    #pragma unroll
    for (int j = 0; j < 8; ++j)
        s[j] = (short)f32_to_bf16_rtn(W[(k0 + j) * HF + col]);
    wfrag[entry] = s;
}

// ---------------- shared GEMM block body (MFMA, 64 rows x 128 cols) ----------------
__device__ __forceinline__ void gemm_body(
    int row0b, char* smem,
    const float* __restrict__ feat, const short8v* __restrict__ wfrag,
    const float* __restrict__ attn_l, const float* __restrict__ attn_r,
    unsigned short* __restrict__ feat_src_h,
    float* __restrict__ el, float* __restrict__ er, int N, int t) {
    unsigned short* a_lds = (unsigned short*)smem;            // 16KB
    unsigned short* w_lds = (unsigned short*)(smem + 16384);  // 32KB
    const int lane = t & 63;
    const int wave = t >> 6;

    {
        const uint4* wsrc = (const uint4*)wfrag;
        uint4* wdst = (uint4*)w_lds;
        #pragma unroll
        for (int i = 0; i < 8; ++i)
            wdst[i * 256 + t] = wsrc[i * 256 + t];
    }
    #pragma unroll
    for (int i = 0; i < 8; ++i) {
        int idx = i * 256 + t;           // float4 index, 0..2047
        int row = idx >> 5;
        int c4  = idx & 31;
        int srow = min(row0b + row, N - 1);
        float4 f = *(const float4*)(feat + (size_t)srow * IN_F + c4 * 4);
        unsigned int lo = ((unsigned int)f32_to_bf16_rtn(f.y) << 16) | f32_to_bf16_rtn(f.x);
        unsigned int hi = ((unsigned int)f32_to_bf16_rtn(f.w) << 16) | f32_to_bf16_rtn(f.z);
        int kb = c4 >> 3, g = (c4 >> 1) & 3, half = c4 & 1;
        int wv = row >> 4, m = row & 15;
        unsigned int* p = (unsigned int*)a_lds;
        int u = (wv * 4096 + kb * 1024 + g * 256 + m * 16 + half * 8) >> 2;
        p[u]     = lo;
        p[u + 1] = hi;
    }
    __syncthreads();

    const int m = lane & 15;
    const int g = lane >> 4;
    short8v aw[4];
    #pragma unroll
    for (int kb = 0; kb < 4; ++kb)
        aw[kb] = *(const short8v*)&a_lds[wave * 2048 + kb * 512 + g * 128 + m * 8];

    f32x4 acc[8];
    #pragma unroll
    for (int nt = 0; nt < 8; ++nt) acc[nt] = (f32x4){0.f, 0.f, 0.f, 0.f};

    #pragma unroll
    for (int nt = 0; nt < 8; ++nt) {
        #pragma unroll
        for (int kb = 0; kb < 4; ++kb) {
            short8v bw = *(const short8v*)&w_lds[((nt * 4 + kb) * 64 + lane) * 8];
            acc[nt] = __builtin_amdgcn_mfma_f32_16x16x32_bf16(aw[kb], bw, acc[nt], 0, 0, 0);
        }
    }

    float al[8], ar[8];
    #pragma unroll
    for (int nt = 0; nt < 8; ++nt) {
        al[nt] = attn_l[nt * 16 + m];
        ar[nt] = attn_r[nt * 16 + m];
    }

    #pragma unroll
    for (int r = 0; r < 4; ++r) {
        const int row = row0b + wave * 16 + 4 * g + r;
        const bool valid = (row < N);
        if (valid) {
            #pragma unroll
            for (int nt = 0; nt < 8; ++nt)
                feat_src_h[(size_t)row * HF + nt * 16 + m] =
                    __half_as_ushort(__float2half(acc[nt][r]));
        }
        float pl[NH], pr[NH];
        #pragma unroll
        for (int h = 0; h < NH; ++h) {
            pl[h] = acc[2 * h][r] * al[2 * h] + acc[2 * h + 1][r] * al[2 * h + 1];
            pr[h] = acc[2 * h][r] * ar[2 * h] + acc[2 * h + 1][r] * ar[2 * h + 1];
        }
        #pragma unroll
        for (int mask = 1; mask <= 8; mask <<= 1) {
            #pragma unroll
            for (int h = 0; h < NH; ++h) {
                pl[h] += __shfl_xor(pl[h], mask);
                pr[h] += __shfl_xor(pr[h], mask);
            }
        }
        if (valid && m == 0) {
            *(float4*)(el + (size_t)row * NH) = make_float4(pl[0], pl[1], pl[2], pl[3]);
            *(float4*)(er + (size_t)row * NH) = make_float4(pr[0], pr[1], pr[2], pr[3]);
        }
    }
}

// ---------------- K3: fused {bin | full MFMA GEMM} ----------------
// Fixed-capacity buckets: bucket b owns gpairs[b*BCAP .. b*BCAP+BCAP).
// gcursor starts at 0; after this kernel gcursor[b] == bucket count.
__global__ void __launch_bounds__(256)
gat_bin_gemm(const int* __restrict__ src, const int* __restrict__ dst,
             int* __restrict__ gcursor, unsigned int* __restrict__ gpairs, int E,
             int nBin,
             const float* __restrict__ feat, const short8v* __restrict__ wfrag,
             const float* __restrict__ attn_l, const float* __restrict__ attn_r,
             unsigned short* __restrict__ feat_src_h,
             float* __restrict__ el, float* __restrict__ er, int N) {
    __shared__ __align__(16) char smem[49152];
    const int t = threadIdx.x;

    if ((int)blockIdx.x < nBin) {
        unsigned int*   stage  = (unsigned int*)smem;                 // 16KB
        unsigned short* buckof = (unsigned short*)(smem + 16384);     // 8KB
        int* hist  = (int*)(smem + 24576);                            // 2KB
        int* sc    = (int*)(smem + 26624);                            // 2KB
        int* basew = (int*)(smem + 28672);                            // 2KB
        int* cur   = (int*)(smem + 30720);                            // 2KB
        for (int i = t; i < 512; i += 256) hist[i] = 0;
        __syncthreads();
        const int e0  = blockIdx.x * BIN_CHUNK;
        const int cnt = min(BIN_CHUNK, E - e0);
        for (int i = t; i < cnt; i += 256)
            atomicAdd(&hist[dst[e0 + i] >> NPB_SHIFT], 1);
        __syncthreads();
        sc[t]       = hist[t];
        sc[t + 256] = hist[t + 256];
        __syncthreads();
        for (int off = 1; off < 512; off <<= 1) {
            int x0 = (t >= off) ? sc[t - off] : 0;
            int x1 = sc[t + 256 - off];
            __syncthreads();
            sc[t]       += x0;
            sc[t + 256] += x1;
            __syncthreads();
        }
        for (int b = t; b < 512; b += 256) {
            int c  = hist[b];
            int ex = sc[b] - c;
            cur[b] = ex;
            basew[b] = c ? (b * BCAP + atomicAdd(&gcursor[b], c)) : 0;
        }
        __syncthreads();
        for (int i = t; i < cnt; i += 256) {
            unsigned s = (unsigned)src[e0 + i];
            unsigned d = (unsigned)dst[e0 + i];
            int b = (int)(d >> NPB_SHIFT);
            int p = atomicAdd(&cur[b], 1);
            stage[p]  = (s << 8) | (d & (NPB - 1));
            buckof[p] = (unsigned short)b;
        }
        __syncthreads();
        for (int j = t; j < cnt; j += 256) {
            int b  = (int)buckof[j];
            int ex = sc[b] - hist[b];
            gpairs[basew[b] + (j - ex)] = stage[j];
        }
        return;
    }

    gemm_body((blockIdx.x - nBin) * 64, smem, feat, wfrag, attn_l, attn_r,
              feat_src_h, el, er, N, t);
}

// ---------------- K4: fused fine+aggregate (one WG per quarter-bucket) ----------------
// Phase A: register-stage the bucket's pairs, build the 64-node CSR in LDS.
// Phase B: single-pass softmax+aggregation (4-group walk) from LDS slots.
__global__ void __launch_bounds__(256)
gat_fine_agg(const unsigned int* __restrict__ gpairs, const int* __restrict__ counts,
             const unsigned short* __restrict__ feat_src_h,
             const float* __restrict__ el, const float* __restrict__ er,
             const float* __restrict__ bias, float* __restrict__ out, int N) {
    __shared__ int   slot_lds[QCAP];
    __shared__ int   hist[64];
    __shared__ int   sbuf[64];
    __shared__ int   offs[65];
    __shared__ int   cur[64];
    __shared__ float exs[4][256];
    const int t = threadIdx.x;
    const int b = blockIdx.x >> 2;
    const int q = blockIdx.x & 3;
    const int node0 = (b << NPB_SHIFT) + q * 64;
    const int beg = b * BCAP;
    const int end = beg + counts[b];

    if (t < 64) hist[t] = 0;
    __syncthreads();

    // ---- phase A: stage pairs in registers, histogram my 64 nodes ----
    unsigned int pv[RP];
    #pragma unroll
    for (int r = 0; r < RP; ++r) {
        int idx = beg + r * 256 + t;
        pv[r] = 0xffffffffu;                       // impossible pair (src < 2^17)
        if (idx < end) {
            unsigned int pr = gpairs[idx];
            pv[r] = pr;
            int local = (int)(pr & (NPB - 1)) - q * 64;
            if (local >= 0 && local < 64) atomicAdd(&hist[local], 1);
        }
    }
    __syncthreads();
    // inclusive scan of hist[0..63]
    if (t < 64) sbuf[t] = hist[t];
    __syncthreads();
    for (int off = 1; off < 64; off <<= 1) {
        int x = (t < 64 && t >= off) ? sbuf[t - off] : 0;
        __syncthreads();
        if (t < 64) sbuf[t] += x;
        __syncthreads();
    }
    if (t < 64) {
        offs[t + 1] = sbuf[t];
        cur[t] = sbuf[t] - hist[t];                // exclusive
        if (t == 0) offs[0] = 0;
    }
    __syncthreads();
    // scatter into LDS CSR
    #pragma unroll
    for (int r = 0; r < RP; ++r) {
        unsigned int pr = pv[r];
        if (pr != 0xffffffffu) {
            int local = (int)(pr & (NPB - 1)) - q * 64;
            if (local >= 0 && local < 64) {
                int p = atomicAdd(&cur[local], 1);
                slot_lds[p] = (int)(pr >> 8);
            }
        }
    }
    __syncthreads();

    // ---- phase B: per-wave node walk (16 nodes per wave) ----
    const int lane = t & 63;
    const int wave = t >> 6;
    const int k  = lane & 15;              // col block: cols 8k..8k+7
    const int g  = lane >> 4;              // edge group 0..3
    const int hm = k >> 2;                 // head of this lane's cols
    const unsigned short* fsp = feat_src_h + 8 * k;
    float* exw = exs[wave];
    float4 b0, b1;
    if (g == 0) {
        b0 = *(const float4*)(bias + 8 * k);
        b1 = *(const float4*)(bias + 8 * k + 4);
    }

    for (int i = 0; i < 16; ++i) {
        const int l = wave + 4 * i;
        const int node = node0 + l;
        if (node >= N) break;
        const int s0 = offs[l];
        const int s1 = offs[l + 1];

        const float4 er4 = *(const float4*)(er + (size_t)node * NH);
        float dacc = 0.f;
        float ax0 = 0.f, ax1 = 0.f, ax2 = 0.f, ax3 = 0.f;
        float ax4 = 0.f, ax5 = 0.f, ax6 = 0.f, ax7 = 0.f;

        for (int c = s0; c < s1; c += 64) {
            int idx = c + lane;
            bool vld = idx < s1;
            int s_l = vld ? slot_lds[idx] : 0;
            float4 ev = make_float4(0.f, 0.f, 0.f, 0.f);
            if (vld) ev = *(const float4*)(el + (size_t)s_l * NH);
            float x0 = ev.x + er4.x; x0 = fmaxf(x0, 0.2f * x0);
            float x1 = ev.y + er4.y; x1 = fmaxf(x1, 0.2f * x1);
            float x2 = ev.z + er4.z; x2 = fmaxf(x2, 0.2f * x2);
            float x3 = ev.w + er4.w; x3 = fmaxf(x3, 0.2f * x3);
            float e0 = vld ? __expf(x0) : 0.f;
            float e1 = vld ? __expf(x1) : 0.f;
            float e2 = vld ? __expf(x2) : 0.f;
            float e3 = vld ? __expf(x3) : 0.f;
            *(float4*)&exw[lane * 4] = make_float4(e0, e1, e2, e3);
            asm volatile("" ::: "memory");
            const int n = min(64, s1 - c);
            int j = g;
            for (; j + 4 < n; j += 8) {
                int jB = j + 4;
                int sA = slot_lds[c + j];
                int sB = slot_lds[c + jB];
                float wA = exw[j * 4 + hm];
                float wB = exw[jB * 4 + hm];
                uint4 uA = *(const uint4*)(fsp + (size_t)sA * HF);
                uint4 uB = *(const uint4*)(fsp + (size_t)sB * HF);
                dacc += wA + wB;
                FMA_MIX_LO(ax0, uA.x, wA); FMA_MIX_LO(ax0, uB.x, wB);
                FMA_MIX_HI(ax1, uA.x, wA); FMA_MIX_HI(ax1, uB.x, wB);
                FMA_MIX_LO(ax2, uA.y, wA); FMA_MIX_LO(ax2, uB.y, wB);
                FMA_MIX_HI(ax3, uA.y, wA); FMA_MIX_HI(ax3, uB.y, wB);
                FMA_MIX_LO(ax4, uA.z, wA); FMA_MIX_LO(ax4, uB.z, wB);
                FMA_MIX_HI(ax5, uA.z, wA); FMA_MIX_HI(ax5, uB.z, wB);
                FMA_MIX_LO(ax6, uA.w, wA); FMA_MIX_LO(ax6, uB.w, wB);
                FMA_MIX_HI(ax7, uA.w, wA); FMA_MIX_HI(ax7, uB.w, wB);
            }
            if (j < n) {
                int sA = slot_lds[c + j];
                float wA = exw[j * 4 + hm];
                uint4 uA = *(const uint4*)(fsp + (size_t)sA * HF);
                dacc += wA;
                FMA_MIX_LO(ax0, uA.x, wA);
                FMA_MIX_HI(ax1, uA.x, wA);
                FMA_MIX_LO(ax2, uA.y, wA);
                FMA_MIX_HI(ax3, uA.y, wA);
                FMA_MIX_LO(ax4, uA.z, wA);
                FMA_MIX_HI(ax5, uA.z, wA);
                FMA_MIX_LO(ax6, uA.w, wA);
                FMA_MIX_HI(ax7, uA.w, wA);
            }
            asm volatile("" ::: "memory");
        }

        // combine 4 edge-groups; dacc becomes denominator for head hm(lane)
        #pragma unroll
        for (int msk = 16; msk <= 32; msk <<= 1) {
            ax0 += __shfl_xor(ax0, msk); ax1 += __shfl_xor(ax1, msk);
            ax2 += __shfl_xor(ax2, msk); ax3 += __shfl_xor(ax3, msk);
            ax4 += __shfl_xor(ax4, msk); ax5 += __shfl_xor(ax5, msk);
            ax6 += __shfl_xor(ax6, msk); ax7 += __shfl_xor(ax7, msk);
            dacc += __shfl_xor(dacc, msk);
        }
        const float inv = 1.0f / fmaxf(dacc, 1e-9f);

        if (g == 0) {
            float4 o0, o1;
            o0.x = ax0 * inv + b0.x; o0.y = ax1 * inv + b0.y;
            o0.z = ax2 * inv + b0.z; o0.w = ax3 * inv + b0.w;
            o1.x = ax4 * inv + b1.x; o1.y = ax5 * inv + b1.y;
            o1.z = ax6 * inv + b1.z; o1.w = ax7 * inv + b1.w;
            *(float4*)(out + (size_t)node * HF + 8 * k)     = o0;
            *(float4*)(out + (size_t)node * HF + 8 * k + 4) = o1;
        }
    }
}

extern "C" void kernel_launch(void* const* d_in, const int* in_sizes, int n_in,
                              void* d_out, int out_size, void* d_ws, size_t ws_size,
                              hipStream_t stream) {
    const float* feat   = (const float*)d_in[0];
    const float* W      = (const float*)d_in[1];
    const float* attn_l = (const float*)d_in[2];
    const float* attn_r = (const float*)d_in[3];
    const float* bias   = (const float*)d_in[4];
    const int*   src    = (const int*)d_in[5];
    const int*   dst    = (const int*)d_in[6];
    float* out = (float*)d_out;

    const int N = in_sizes[0] / IN_F;
    const int E = in_sizes[5];
    const int nbuck = (N + NPB - 1) / NPB;      // 391 for N=100000

    char* ws = (char*)d_ws;
    size_t off = 0;
    auto alloc = [&](size_t bytes) -> void* {
        off = (off + 255) & ~(size_t)255;
        void* p = ws + off;
        off += bytes;
        return p;
    };
    unsigned short* feat_src_h = (unsigned short*)alloc((size_t)N * HF * sizeof(unsigned short));
    float* el      = (float*)alloc((size_t)N * NH * sizeof(float));
    float* er      = (float*)alloc((size_t)N * NH * sizeof(float));
    int*   gcursor = (int*)  alloc((size_t)nbuck * sizeof(int));
    unsigned int* gpairs = (unsigned int*)alloc((size_t)nbuck * BCAP * sizeof(unsigned int));
    short8v* wfrag = (short8v*)alloc((size_t)2048 * sizeof(short8v));   // 32KB

    hipMemsetAsync(gcursor, 0, (size_t)nbuck * sizeof(int), stream);

    gat_wfrag<<<8, 256, 0, stream>>>(W, wfrag);

    const int nBin = (E + BIN_CHUNK - 1) / BIN_CHUNK;
    const int gemmBlocks = (N + 63) / 64;
    gat_bin_gemm<<<nBin + gemmBlocks, 256, 0, stream>>>(
        src, dst, gcursor, gpairs, E, nBin,
        feat, wfrag, attn_l, attn_r, feat_src_h, el, er, N);

    gat_fine_agg<<<nbuck * 4, 256, 0, stream>>>(
        gpairs, gcursor, feat_src_h, el, er, bias, out, N);
}